// Round 6
// baseline (28977.344 us; speedup 1.0000x reference)
//
#include <hip/hip_runtime.h>
#include <hip/hip_bf16.h>
#include <stdint.h>

typedef unsigned int u32;
typedef unsigned long long u64;
typedef __attribute__((ext_vector_type(8))) short short8;
typedef __attribute__((ext_vector_type(4))) float floatx4;
typedef __attribute__((ext_vector_type(2))) unsigned long long u64x2;

#define T_STEPS 4096
#define N_IN    512
#define N_H     1024
#define G_LAUNCH 256         // launched scan WGs; 32 elected (one XCD) participate
#define THREADS  128         // 2 waves per WG, 32 cols per WG
#define WINNERS  32
#define MB_WORDS 8192        // mailbox: word W = pair*16 + batch (batch 15 phantom)

// ---------- ws layout (bytes) ----------
#define OFF_XP    0
#define OFF_WIHB  (134217728)
#define OFF_HTAG  (134217728 + 1048576)
#define OFF_CLAIM (134217728 + 1048576 + 2*MB_WORDS*8)   // u32[16]

__device__ inline u32 f2bf1(float f) {            // fp32 -> bf16 (RNE), as u32
    u32 u = __builtin_bit_cast(u32, f);
    return (u + 0x7FFFu + ((u >> 16) & 1u)) >> 16;
}
__device__ inline float bf2f(u32 us) {            // bf16 (low 16) -> fp32
    return __builtin_bit_cast(float, us << 16);
}
__device__ inline float tanh_fast(float x) {
    float e = __expf(2.0f * x);                   // inf-safe at both ends
    return 1.0f - 2.0f / (e + 1.0f);
}
// Poll load: agent scope — bypasses L1, reads the shared same-XCD L2 (proven R4/R5).
__device__ inline u64 mb_load(const u64* p) {
    return __hip_atomic_load(p, __ATOMIC_RELAXED, __HIP_MEMORY_SCOPE_AGENT);
}

// ---------------- kernel 0: convert W_ih to packed bf16 (+ zero election block) ----------------
__global__ void k_cvt_wih(const float* __restrict__ W_ih, u32* __restrict__ wihb,
                          u32* __restrict__ claim) {
    if (blockIdx.x == 0 && threadIdx.x < 16) claim[threadIdx.x] = 0;
    int row = blockIdx.x;
    int tid = threadIdx.x;
    const float* p = W_ih + (size_t)row * N_IN + tid * 2;
    u32 packed = f2bf1(p[0]) | (f2bf1(p[1]) << 16);
    wihb[row * (N_IN / 2) + tid] = packed;
}

// ---------------- kernel 1: x_proj GEMM ----------------
// xp[((t*64 + cw)*64 + lane)] = bf16x4 (rows quad*4+i, col cw*16+(l&15))
__global__ void __launch_bounds__(256) k_xproj(
        const float* __restrict__ x, const u32* __restrict__ wihb,
        const float* __restrict__ b_ih, const float* __restrict__ b_hh,
        u64* __restrict__ xp) {
    const int t     = blockIdx.x;
    const int slice = blockIdx.y;
    const int tid   = threadIdx.x;
    const int wave  = tid >> 6;
    const int l     = tid & 63;
    const int row   = l & 15;       // batch
    const int quad  = l >> 4;
    const int colbase = slice * 256 + wave * 64;

    floatx4 acc[4] = {{0,0,0,0},{0,0,0,0},{0,0,0,0},{0,0,0,0}};
    const float* xrow = x + ((size_t)row * T_STEPS + t) * N_IN;

    #pragma unroll
    for (int kk = 0; kk < 16; ++kk) {
        short8 a;
        if (row < 15) {
            const float* pa = xrow + kk * 32 + quad * 8;
            float4 x0 = *(const float4*)(pa);
            float4 x1 = *(const float4*)(pa + 4);
            a[0]=(short)f2bf1(x0.x); a[1]=(short)f2bf1(x0.y); a[2]=(short)f2bf1(x0.z); a[3]=(short)f2bf1(x0.w);
            a[4]=(short)f2bf1(x1.x); a[5]=(short)f2bf1(x1.y); a[6]=(short)f2bf1(x1.z); a[7]=(short)f2bf1(x1.w);
        } else {
            #pragma unroll
            for (int j = 0; j < 8; ++j) a[j] = 0;
        }
        #pragma unroll
        for (int c4 = 0; c4 < 4; ++c4) {
            int col = colbase + c4 * 16 + (l & 15);
            const uint4* pb = (const uint4*)(wihb + (size_t)col * (N_IN/2) + kk * 16 + quad * 4);
            short8 b = __builtin_bit_cast(short8, *pb);
            acc[c4] = __builtin_amdgcn_mfma_f32_16x16x32_bf16(a, b, acc[c4], 0, 0, 0);
        }
    }
    #pragma unroll
    for (int c4 = 0; c4 < 4; ++c4) {
        int col = colbase + c4 * 16 + (l & 15);
        float bias = b_ih[col] + b_hh[col];
        u64 packed = (u64)f2bf1(acc[c4][0] + bias)
                   | ((u64)f2bf1(acc[c4][1] + bias) << 16)
                   | ((u64)f2bf1(acc[c4][2] + bias) << 32)
                   | ((u64)f2bf1(acc[c4][3] + bias) << 48);
        int cw = slice * 16 + wave * 4 + c4;
        xp[((size_t)t * 64 + cw) * 64 + l] = packed;
    }
}

// ---------------- scan poll helpers ----------------
__device__ __forceinline__ void poll_issue(const u64* buf, u64 (&v)[16], int ph, int tid) {
    #pragma unroll
    for (int j = 0; j < 16; ++j)
        v[j] = mb_load(buf + tid + 128 * (ph * 16 + j));
}
__device__ __forceinline__ void poll_resolve(const u64* buf, u64 (&v)[16], int ph, u32 tag,
                                             int tid, int pa, int pb, bool b15,
                                             u32* lds, int* dead) {
    u32 got = b15 ? 0xFFFFu : 0u;
    int rounds = 0;
    while (got != 0xFFFFu) {
        #pragma unroll
        for (int j = 0; j < 16; ++j) {
            if (!((got >> j) & 1) && (u32)(v[j] >> 32) == tag) {
                got |= 1u << j;
                int p = pa + 8 * (ph * 16 + j);     // pair index 0..511
                lds[(p >> 4) * 256 + ((p >> 2) & 3) * 64 + (p & 3) + pb * 4] = (u32)v[j];
            }
        }
        if (got == 0xFFFFu) break;
        if (++rounds > (1 << 20)) { *dead = 1; break; }
        #pragma unroll
        for (int j = 0; j < 16; ++j)
            if (!((got >> j) & 1))
                v[j] = mb_load(buf + tid + 128 * (ph * 16 + j));
    }
}

// ---------------- kernel 2: sequential scan (32 elected WGs on ONE XCD) ----------------
__global__ void __launch_bounds__(THREADS, 1) k_scan(
        const float* __restrict__ W_hh, const u64* __restrict__ xp,
        u64* __restrict__ htag, u32* __restrict__ claim,
        const float* __restrict__ W_fc, const float* __restrict__ b_fc,
        float* __restrict__ out) {
    __shared__ u32 hA[2][MB_WORDS];   // A-frag layout: idx = kk*256 + quad*64 + (p&3) + batch*4
    __shared__ float red[8];
    __shared__ int s_slot;
    __shared__ int s_dead;

    const int tid  = threadIdx.x;      // 0..127
    const int wave = tid >> 6;
    const int l    = tid & 63;
    const int c    = l & 15;           // col-in-tile (B/C role) == A row (batch role)
    const int quad = l >> 4;
    const int pb   = tid & 15;         // mailbox batch owned by this poll thread
    const int pa   = tid >> 4;         // 0..7
    const bool b15 = (pb == 15);       // phantom batch — nothing to poll

    // ---- XCD election: first XCD to accumulate 32 WGs wins ----
    if (tid == 0) {
        u32 xcd;
        asm volatile("s_getreg_b32 %0, hwreg(HW_REG_XCC_ID)" : "=s"(xcd));
        xcd &= 7u;
        u32 slot = __hip_atomic_fetch_add(&claim[xcd], 1u, __ATOMIC_RELAXED,
                                          __HIP_MEMORY_SCOPE_AGENT);
        if (slot == WINNERS - 1) {
            u32 exp = 0u;
            __hip_atomic_compare_exchange_strong(&claim[8], &exp, xcd + 1u,
                __ATOMIC_RELAXED, __ATOMIC_RELAXED, __HIP_MEMORY_SCOPE_AGENT);
        }
        u32 w = 0; int gg = 0;
        do { w = __hip_atomic_load(&claim[8], __ATOMIC_RELAXED, __HIP_MEMORY_SCOPE_AGENT); }
        while (!w && ++gg < (1 << 22));
        s_slot = (w == xcd + 1u && slot < (u32)WINNERS) ? (int)slot : -1;
        s_dead = 0;
    }
    __syncthreads();
    const int g = s_slot;              // 0..31 for participants
    if (g < 0) return;

    const int col = g * 32 + wave * 16 + c;   // this lane's output column
    const int cw  = g * 2 + wave;             // xp col-tile index

    // --- W_hh fragments permanently in registers (128 VGPRs/lane) ---
    short8 wf[32];
    {
        const float* wr = W_hh + (size_t)col * N_H;
        #pragma unroll
        for (int kk = 0; kk < 32; ++kk) {
            const float* p = wr + kk * 32 + quad * 8;
            float4 w0 = *(const float4*)(p);
            float4 w1 = *(const float4*)(p + 4);
            short8 bfr;
            bfr[0]=(short)f2bf1(w0.x); bfr[1]=(short)f2bf1(w0.y); bfr[2]=(short)f2bf1(w0.z); bfr[3]=(short)f2bf1(w0.w);
            bfr[4]=(short)f2bf1(w1.x); bfr[5]=(short)f2bf1(w1.y); bfr[6]=(short)f2bf1(w1.z); bfr[7]=(short)f2bf1(w1.w);
            wf[kk] = bfr;
        }
    }
    for (int i = tid; i < 2 * MB_WORDS; i += THREADS) ((u32*)hA)[i] = 0;
    __syncthreads();

    // ---- step 0: h(1) = tanh(xp(0)); publish tag 1 (parity 1) ----
    u64 xpw = xp[((size_t)0 * 64 + cw) * 64 + l];
    float h[4];
    {
        h[0] = tanh_fast(bf2f((u32)(xpw      ) & 0xFFFFu));
        h[1] = tanh_fast(bf2f((u32)(xpw >> 16) & 0xFFFFu));
        h[2] = tanh_fast(bf2f((u32)(xpw >> 32) & 0xFFFFu));
        h[3] = tanh_fast(bf2f((u32)(xpw >> 48) & 0xFFFFu));
        u64* bufw = htag + (size_t)1 * MB_WORDS;
        u64 wv[4];
        #pragma unroll
        for (int i = 0; i < 4; ++i) {
            float o = __shfl_xor(h[i], 1);
            wv[i] = ((u64)1u << 32) | (u64)(f2bf1(h[i]) | (f2bf1(o) << 16));
        }
        if (!(c & 1)) {
            u64* dst = bufw + (size_t)(col >> 1) * 16 + quad * 4;
            *(u64x2*)dst       = u64x2{wv[0], wv[1]};
            *(u64x2*)(dst + 2) = u64x2{wv[2], wv[3]};
        }
    }
    u64 xpw_n = xp[((size_t)1 * 64 + cw) * 64 + l];

    for (int s = 1; s < T_STEPS; ++s) {
        xpw = xpw_n;
        const u64* buf = htag + (size_t)(s & 1) * MB_WORDS;
        u32* lds = &hA[s & 1][0];
        const u32 tag = (u32)s;

        // ---- poll: 64 words/lane, 4 ping-ponged phases of 16 ----
        u64 va[16], vb[16];
        if (!b15) { poll_issue(buf, va, 0, tid); poll_issue(buf, vb, 1, tid); }
        poll_resolve(buf, va, 0, tag, tid, pa, pb, b15, lds, &s_dead);
        if (!b15) poll_issue(buf, va, 2, tid);
        poll_resolve(buf, vb, 1, tag, tid, pa, pb, b15, lds, &s_dead);
        if (!b15) poll_issue(buf, vb, 3, tid);
        poll_resolve(buf, va, 2, tag, tid, pa, pb, b15, lds, &s_dead);
        poll_resolve(buf, vb, 3, tag, tid, pa, pb, b15, lds, &s_dead);
        __syncthreads();               // the ONLY barrier per step
        if (s_dead) break;

        // ---- compute: fully-unrolled dual-accumulator MFMA chain ----
        floatx4 acc0, acc1;
        acc0[0] = bf2f((u32)(xpw      ) & 0xFFFFu);
        acc0[1] = bf2f((u32)(xpw >> 16) & 0xFFFFu);
        acc0[2] = bf2f((u32)(xpw >> 32) & 0xFFFFu);
        acc0[3] = bf2f((u32)(xpw >> 48) & 0xFFFFu);
        acc1[0] = 0.f; acc1[1] = 0.f; acc1[2] = 0.f; acc1[3] = 0.f;

        #pragma unroll
        for (int kk = 0; kk < 32; kk += 2) {
            uint4 a0 = *(const uint4*)&lds[(kk    ) * 256 + quad * 64 + c * 4];
            uint4 a1 = *(const uint4*)&lds[(kk + 1) * 256 + quad * 64 + c * 4];
            acc0 = __builtin_amdgcn_mfma_f32_16x16x32_bf16(
                       __builtin_bit_cast(short8, a0), wf[kk    ], acc0, 0, 0, 0);
            acc1 = __builtin_amdgcn_mfma_f32_16x16x32_bf16(
                       __builtin_bit_cast(short8, a1), wf[kk + 1], acc1, 0, 0, 0);
        }

        if (s + 1 < T_STEPS) xpw_n = xp[((size_t)(s + 1) * 64 + cw) * 64 + l];

        #pragma unroll
        for (int i = 0; i < 4; ++i) h[i] = tanh_fast(acc0[i] + acc1[i]);

        // ---- publish h(s+1): two contiguous plain 16B stores -> local L2 ----
        u64* bufw = htag + (size_t)((s + 1) & 1) * MB_WORDS;
        const u32 tag1 = (u32)(s + 1);
        u64 wv[4];
        #pragma unroll
        for (int i = 0; i < 4; ++i) {
            float o = __shfl_xor(h[i], 1);
            wv[i] = ((u64)tag1 << 32) | (u64)(f2bf1(h[i]) | (f2bf1(o) << 16));
        }
        if (!(c & 1)) {
            u64* dst = bufw + (size_t)(col >> 1) * 16 + quad * 4;
            *(u64x2*)dst       = u64x2{wv[0], wv[1]};
            *(u64x2*)(dst + 2) = u64x2{wv[2], wv[3]};
        }
    }

    // ---------------- epilogue: elected WG 0 computes the sigmoid head ----------------
    if (g == 0) {
        const u64* fbuf = htag + (size_t)(T_STEPS & 1) * MB_WORDS;  // parity 0
        const u32 ftag = (u32)T_STEPS;
        for (int bi = 0; bi < 15; ++bi) {
            float sum = 0.f;
            #pragma unroll
            for (int j = 0; j < 4; ++j) {
                int p = tid * 4 + j;                 // pair index 0..511
                const u64* wp = fbuf + (size_t)p * 16 + bi;
                u64 wv2 = mb_load(wp);
                int guard = 0;
                while ((u32)(wv2 >> 32) != ftag && ++guard < (1 << 20)) wv2 = mb_load(wp);
                sum += bf2f((u32)wv2 & 0xFFFFu) * W_fc[2 * p]
                     + bf2f(((u32)wv2 >> 16) & 0xFFFFu) * W_fc[2 * p + 1];
            }
            #pragma unroll
            for (int off = 32; off; off >>= 1) sum += __shfl_down(sum, off);
            if (l == 0) red[wave] = sum;
            __syncthreads();
            if (tid == 0) out[bi] = 1.0f / (1.0f + __expf(-(red[0] + red[1] + b_fc[0])));
            __syncthreads();
        }
    }
}

extern "C" void kernel_launch(void* const* d_in, const int* in_sizes, int n_in,
                              void* d_out, int out_size, void* d_ws, size_t ws_size,
                              hipStream_t stream) {
    const float* x    = (const float*)d_in[0];
    const float* W_ih = (const float*)d_in[1];
    const float* b_ih = (const float*)d_in[2];
    const float* W_hh = (const float*)d_in[3];
    const float* b_hh = (const float*)d_in[4];
    const float* W_fc = (const float*)d_in[5];
    const float* b_fc = (const float*)d_in[6];
    float* out = (float*)d_out;

    char* ws    = (char*)d_ws;
    u64*  xp    = (u64*)(ws + OFF_XP);
    u32*  wihb  = (u32*)(ws + OFF_WIHB);
    u64*  htag  = (u64*)(ws + OFF_HTAG);
    u32*  claim = (u32*)(ws + OFF_CLAIM);

    k_cvt_wih<<<dim3(N_H), dim3(256), 0, stream>>>(W_ih, wihb, claim);
    k_xproj<<<dim3(T_STEPS, 4), dim3(256), 0, stream>>>(x, wihb, b_ih, b_hh, xp);
    k_scan<<<dim3(G_LAUNCH), dim3(THREADS), 0, stream>>>(W_hh, xp, htag, claim, W_fc, b_fc, out);
}